// Round 1
// baseline (426.363 us; speedup 1.0000x reference)
//
#include <hip/hip_runtime.h>

typedef __bf16 bf16x8 __attribute__((ext_vector_type(8)));
typedef float f32x4 __attribute__((ext_vector_type(4)));
typedef unsigned int u32x4 __attribute__((ext_vector_type(4)));

__device__ __forceinline__ unsigned short f2bf(float f) {
  unsigned int u = __builtin_bit_cast(unsigned int, f);
  u += 0x7fffu + ((u >> 16) & 1u);   // RNE
  return (unsigned short)(u >> 16);
}
__device__ __forceinline__ float bf2f(unsigned short h) {
  unsigned int u = ((unsigned int)h) << 16;
  return __builtin_bit_cast(float, u);
}

// ---------------- x -> bf16 ----------------
__global__ __launch_bounds__(256) void cvt_f32_bf16(const float* __restrict__ src,
                                                    unsigned short* __restrict__ dst, int n4) {
  int i = blockIdx.x * 256 + threadIdx.x;
  if (i >= n4) return;
  float4 v = ((const float4*)src)[i];
  uint2 o;
  o.x = (unsigned)f2bf(v.x) | ((unsigned)f2bf(v.y) << 16);
  o.y = (unsigned)f2bf(v.z) | ((unsigned)f2bf(v.w) << 16);
  ((uint2*)dst)[i] = o;
}

// ---------------- W[K][N] fp32 -> Wt[N][K] bf16 (LDS-tiled) ----------------
__global__ __launch_bounds__(256) void transpose_cvt(const float* __restrict__ src,
                                                     unsigned short* __restrict__ dst,
                                                     int R, int C) {
  __shared__ float tile[32][33];
  int c0 = blockIdx.x * 32, r0 = blockIdx.y * 32;
  int tx = threadIdx.x & 31, ty = threadIdx.x >> 5;
#pragma unroll
  for (int i = 0; i < 4; ++i)
    tile[ty + i * 8][tx] = src[(r0 + ty + i * 8) * C + c0 + tx];
  __syncthreads();
#pragma unroll
  for (int i = 0; i < 4; ++i)
    dst[(c0 + ty + i * 8) * R + r0 + tx] = f2bf(tile[tx][ty + i * 8]);
}

// ---------------- GEMM: C[M][N] = A[M][K](bf16) @ Bt[N][K](bf16)^T ----------------
// 128x128 tile, 256 threads (4 waves, 2x2), each wave 64x64 = 4x4 MFMA tiles, BK=32.
__global__ __launch_bounds__(256) void gemm_bt(const unsigned short* __restrict__ A,
                                               const unsigned short* __restrict__ Bt,
                                               void* __restrict__ Cout,
                                               int M, int N, int K, int outF32) {
  __shared__ __align__(16) unsigned short Als[128 * 40];  // stride 40 (80B rows, 16B-aligned)
  __shared__ __align__(16) unsigned short Bls[128 * 40];
  const int tid = threadIdx.x;
  const int wave = tid >> 6, lane = tid & 63;
  const int lgrp = lane >> 4, lmod = lane & 15;
  const int wm = (wave & 1) * 64, wn = (wave >> 1) * 64;
  const int m0 = blockIdx.y * 128, n0 = blockIdx.x * 128;
  const int srow = tid >> 2;        // 0..63
  const int sq = (tid & 3) * 8;     // ushort offset

  f32x4 acc[4][4] = {};

  for (int k0 = 0; k0 < K; k0 += 32) {
    __syncthreads();
#pragma unroll
    for (int it = 0; it < 2; ++it) {
      int r = srow + it * 64;
      *(u32x4*)&Als[r * 40 + sq] = *(const u32x4*)&A[(m0 + r) * K + k0 + sq];
      *(u32x4*)&Bls[r * 40 + sq] = *(const u32x4*)&Bt[(n0 + r) * K + k0 + sq];
    }
    __syncthreads();
    bf16x8 af[4], bfr[4];
#pragma unroll
    for (int mi = 0; mi < 4; ++mi)
      af[mi] = __builtin_bit_cast(bf16x8, *(const u32x4*)&Als[(wm + mi * 16 + lmod) * 40 + lgrp * 8]);
#pragma unroll
    for (int ni = 0; ni < 4; ++ni)
      bfr[ni] = __builtin_bit_cast(bf16x8, *(const u32x4*)&Bls[(wn + ni * 16 + lmod) * 40 + lgrp * 8]);
#pragma unroll
    for (int mi = 0; mi < 4; ++mi)
#pragma unroll
      for (int ni = 0; ni < 4; ++ni)
        acc[mi][ni] = __builtin_amdgcn_mfma_f32_16x16x32_bf16(af[mi], bfr[ni], acc[mi][ni], 0, 0, 0);
  }

#pragma unroll
  for (int mi = 0; mi < 4; ++mi)
#pragma unroll
    for (int ni = 0; ni < 4; ++ni)
#pragma unroll
      for (int r = 0; r < 4; ++r) {
        int row = m0 + wm + mi * 16 + lgrp * 4 + r;
        int col = n0 + wn + ni * 16 + lmod;
        float v = acc[mi][ni][r];
        if (outF32) ((float*)Cout)[row * N + col] = v;
        else ((unsigned short*)Cout)[row * N + col] = f2bf(v);
      }
}

// ---------------- RoPE + split Q/K ----------------
// qkv[4096][1536] bf16; cols 0..1023 = Q(16 heads), 1024..1279 = K(4 heads).
__global__ __launch_bounds__(256) void rope_split(const unsigned short* __restrict__ qkv,
                                                  const float* __restrict__ sinT,
                                                  const float* __restrict__ cosT,
                                                  unsigned short* __restrict__ Qh,
                                                  unsigned short* __restrict__ Kh) {
  int p = blockIdx.x * 256 + threadIdx.x;   // pair index over 4096*640
  int s = p / 640, cp = p % 640;
  int col = cp * 2;
  unsigned int pair = *(const unsigned int*)&qkv[s * 1536 + col];
  float e = bf2f((unsigned short)(pair & 0xffff));
  float o = bf2f((unsigned short)(pair >> 16));
  if (col < 1024) {
    int h = col >> 6, d = col & 63, i = d >> 1;
    float sn = sinT[s * 32 + i], cs = cosT[s * 32 + i];
    unsigned int w = (unsigned)f2bf(cs * e - sn * o) | ((unsigned)f2bf(sn * e + cs * o) << 16);
    *(unsigned int*)&Qh[(h * 4096 + s) * 64 + d] = w;
  } else {
    int c = col - 1024;
    int h = c >> 6, d = c & 63, i = d >> 1;
    float sn = sinT[s * 32 + i], cs = cosT[s * 32 + i];
    unsigned int w = (unsigned)f2bf(cs * e - sn * o) | ((unsigned)f2bf(sn * e + cs * o) << 16);
    *(unsigned int*)&Kh[(h * 4096 + s) * 64 + d] = w;
  }
}

// ---------------- V transpose: qkv cols 1280..1535 -> Vt[4][64][4096] ----------------
__global__ __launch_bounds__(256) void transpose_v(const unsigned short* __restrict__ qkv,
                                                   unsigned short* __restrict__ Vt) {
  __shared__ unsigned short tile[32][33];
  int h = blockIdx.z;
  int d0 = blockIdx.y * 32;
  int s0 = blockIdx.x * 32;
  int tx = threadIdx.x & 31, ty = threadIdx.x >> 5;
#pragma unroll
  for (int i = 0; i < 4; ++i)
    tile[ty + i * 8][tx] = qkv[(s0 + ty + i * 8) * 1536 + 1280 + h * 64 + d0 + tx];
  __syncthreads();
#pragma unroll
  for (int i = 0; i < 4; ++i)
    Vt[(h * 64 + d0 + ty + i * 8) * 4096 + s0 + tx] = tile[tx][ty + i * 8];
}

// ---------------- Flash attention (causal, start=0) ----------------
// grid (64 q-tiles, 16 heads), block 256 = 4 waves; wave w owns q rows [qbase+16w, +16).
__global__ __launch_bounds__(256) void attn(const unsigned short* __restrict__ Qh,
                                            const unsigned short* __restrict__ Kh,
                                            const unsigned short* __restrict__ Vt,
                                            unsigned short* __restrict__ ctx) {
  __shared__ __align__(16) unsigned short Kls[64 * 72];      // [key][d], stride 72
  __shared__ __align__(16) unsigned short Vls[64 * 72];      // [d][key], stride 72
  __shared__ __align__(16) unsigned short Pls[4][16 * 72];   // per-wave P, stride 72
  const int qi = blockIdx.x, head = blockIdx.y;
  const int kvh = head >> 2;
  const int tid = threadIdx.x;
  const int wave = tid >> 6, lane = tid & 63;
  const int lgrp = lane >> 4, lmod = lane & 15;
  const int qbase = qi * 64;

  const unsigned short* Qg = Qh + (size_t)(head * 4096 + qbase + wave * 16 + lmod) * 64;
  bf16x8 qf0 = __builtin_bit_cast(bf16x8, *(const u32x4*)&Qg[lgrp * 8]);
  bf16x8 qf1 = __builtin_bit_cast(bf16x8, *(const u32x4*)&Qg[32 + lgrp * 8]);
  const unsigned short* Kg = Kh + (size_t)kvh * 4096 * 64;
  const unsigned short* Vg = Vt + (size_t)kvh * 64 * 4096;

  f32x4 accO[4] = {};
  float m_i[4], l_i[4];
#pragma unroll
  for (int r = 0; r < 4; ++r) { m_i[r] = -1e30f; l_i[r] = 0.f; }

  const int srow = tid >> 2;      // 0..63
  const int sq = (tid & 3) * 8;

  for (int kc = 0; kc <= qi; ++kc) {
    const int kb = kc * 64;
    __syncthreads();
#pragma unroll
    for (int it = 0; it < 2; ++it) {
      int dq = sq + it * 32;
      *(u32x4*)&Kls[srow * 72 + dq] = *(const u32x4*)&Kg[(kb + srow) * 64 + dq];   // [key][d]
      *(u32x4*)&Vls[srow * 72 + dq] = *(const u32x4*)&Vg[srow * 4096 + kb + dq];   // [d][key]
    }
    __syncthreads();

    // S = Q @ K^T  (k-dim = d, n-dim = key)
    f32x4 s[4];
#pragma unroll
    for (int t = 0; t < 4; ++t) {
      bf16x8 b0 = __builtin_bit_cast(bf16x8, *(const u32x4*)&Kls[(t * 16 + lmod) * 72 + lgrp * 8]);
      bf16x8 b1 = __builtin_bit_cast(bf16x8, *(const u32x4*)&Kls[(t * 16 + lmod) * 72 + 32 + lgrp * 8]);
      f32x4 z = {};
      z = __builtin_amdgcn_mfma_f32_16x16x32_bf16(qf0, b0, z, 0, 0, 0);
      z = __builtin_amdgcn_mfma_f32_16x16x32_bf16(qf1, b1, z, 0, 0, 0);
      s[t] = z;
    }

    float sv[4][4];
    const bool diag = (kc == qi);
#pragma unroll
    for (int t = 0; t < 4; ++t)
#pragma unroll
      for (int r = 0; r < 4; ++r) {
        float v = s[t][r] * 0.125f;
        if (diag) {
          int rowl = wave * 16 + lgrp * 4 + r;
          int coll = t * 16 + lmod;
          if (coll > rowl) v = -1e30f;
        }
        sv[t][r] = v;
      }

#pragma unroll
    for (int r = 0; r < 4; ++r) {
      float mx = fmaxf(fmaxf(sv[0][r], sv[1][r]), fmaxf(sv[2][r], sv[3][r]));
#pragma unroll
      for (int off = 1; off < 16; off <<= 1) mx = fmaxf(mx, __shfl_xor(mx, off, 64));
      float mnew = fmaxf(m_i[r], mx);
      float alpha = __expf(m_i[r] - mnew);
      m_i[r] = mnew;
      float rs = 0.f;
#pragma unroll
      for (int t = 0; t < 4; ++t) {
        float pexp = __expf(sv[t][r] - mnew);
        sv[t][r] = pexp;
        rs += pexp;
      }
#pragma unroll
      for (int off = 1; off < 16; off <<= 1) rs += __shfl_xor(rs, off, 64);
      l_i[r] = l_i[r] * alpha + rs;
#pragma unroll
      for (int t = 0; t < 4; ++t) accO[t][r] *= alpha;
    }

    // P: C-layout -> LDS -> A-layout
#pragma unroll
    for (int t = 0; t < 4; ++t)
#pragma unroll
      for (int r = 0; r < 4; ++r)
        Pls[wave][(lgrp * 4 + r) * 72 + t * 16 + lmod] = f2bf(sv[t][r]);
    __asm__ volatile("s_waitcnt lgkmcnt(0)" ::: "memory");
    bf16x8 pa0 = __builtin_bit_cast(bf16x8, *(const u32x4*)&Pls[wave][lmod * 72 + lgrp * 8]);
    bf16x8 pa1 = __builtin_bit_cast(bf16x8, *(const u32x4*)&Pls[wave][lmod * 72 + 32 + lgrp * 8]);

    // O += P @ V   (k-dim = key, n-dim = d); V[k][n] = Vls[n][k]
#pragma unroll
    for (int t = 0; t < 4; ++t) {
      bf16x8 vb0 = __builtin_bit_cast(bf16x8, *(const u32x4*)&Vls[(t * 16 + lmod) * 72 + lgrp * 8]);
      bf16x8 vb1 = __builtin_bit_cast(bf16x8, *(const u32x4*)&Vls[(t * 16 + lmod) * 72 + 32 + lgrp * 8]);
      accO[t] = __builtin_amdgcn_mfma_f32_16x16x32_bf16(pa0, vb0, accO[t], 0, 0, 0);
      accO[t] = __builtin_amdgcn_mfma_f32_16x16x32_bf16(pa1, vb1, accO[t], 0, 0, 0);
    }
  }

#pragma unroll
  for (int r = 0; r < 4; ++r) {
    float inv = 1.f / l_i[r];
    int row = qbase + wave * 16 + lgrp * 4 + r;
#pragma unroll
    for (int t = 0; t < 4; ++t)
      ctx[(size_t)row * 1024 + head * 64 + t * 16 + lmod] = f2bf(accO[t][r] * inv);
  }
}

extern "C" void kernel_launch(void* const* d_in, const int* in_sizes, int n_in,
                              void* d_out, int out_size, void* d_ws, size_t ws_size,
                              hipStream_t stream) {
  const float* x    = (const float*)d_in[0];
  const float* wq   = (const float*)d_in[3];
  const float* wk   = (const float*)d_in[4];
  const float* wv   = (const float*)d_in[5];
  const float* wo   = (const float*)d_in[6];
  const float* sinT = (const float*)d_in[7];
  const float* cosT = (const float*)d_in[8];

  unsigned short* ws    = (unsigned short*)d_ws;
  unsigned short* xb    = ws;                          // 4096*1024
  unsigned short* wtqkv = xb + 4096 * 1024;            // 1536*1024 (Wq^T|Wk^T|Wv^T)
  unsigned short* wot   = wtqkv + 1536 * 1024;         // 1024*1024
  unsigned short* qkv   = wot + 1024 * 1024;           // 4096*1536
  unsigned short* Qh    = qkv + 4096 * 1536;           // 16*4096*64
  unsigned short* Kh    = Qh + 16 * 4096 * 64;         // 4*4096*64
  unsigned short* Vt    = Kh + 4 * 4096 * 64;          // 4*64*4096
  unsigned short* ctx   = Vt + 4 * 64 * 4096;          // 4096*1024
  float* out = (float*)d_out;

  cvt_f32_bf16<<<4096, 256, 0, stream>>>(x, xb, 4096 * 1024 / 4);
  transpose_cvt<<<dim3(32, 32), 256, 0, stream>>>(wq, wtqkv, 1024, 1024);
  transpose_cvt<<<dim3(8, 32), 256, 0, stream>>>(wk, wtqkv + 1024 * 1024, 1024, 256);
  transpose_cvt<<<dim3(8, 32), 256, 0, stream>>>(wv, wtqkv + 1280 * 1024, 1024, 256);
  transpose_cvt<<<dim3(32, 32), 256, 0, stream>>>(wo, wot, 1024, 1024);

  gemm_bt<<<dim3(12, 32), 256, 0, stream>>>(xb, wtqkv, qkv, 4096, 1536, 1024, 0);

  rope_split<<<10240, 256, 0, stream>>>(qkv, sinT, cosT, Qh, Kh);
  transpose_v<<<dim3(128, 2, 4), 256, 0, stream>>>(qkv, Vt);

  attn<<<dim3(64, 16), 256, 0, stream>>>(Qh, Kh, Vt, ctx);

  gemm_bt<<<dim3(8, 32), 256, 0, stream>>>(ctx, wot, out, 4096, 1024, 1024, 1);
}

// Round 2
// 308.292 us; speedup vs baseline: 1.3830x; 1.3830x over previous
//
#include <hip/hip_runtime.h>

typedef __bf16 bf16x8 __attribute__((ext_vector_type(8)));
typedef float f32x4 __attribute__((ext_vector_type(4)));
typedef unsigned int u32x4 __attribute__((ext_vector_type(4)));

__device__ __forceinline__ unsigned short f2bf(float f) {
  unsigned int u = __builtin_bit_cast(unsigned int, f);
  u += 0x7fffu + ((u >> 16) & 1u);   // RNE
  return (unsigned short)(u >> 16);
}
__device__ __forceinline__ float bf2f(unsigned short h) {
  unsigned int u = ((unsigned int)h) << 16;
  return __builtin_bit_cast(float, u);
}
__device__ __forceinline__ unsigned int pack2bf(float lo, float hi) {
  return (unsigned int)f2bf(lo) | ((unsigned int)f2bf(hi) << 16);
}

// ---------------- x -> bf16 ----------------
__global__ __launch_bounds__(256) void cvt_f32_bf16(const float* __restrict__ src,
                                                    unsigned short* __restrict__ dst, int n4) {
  int i = blockIdx.x * 256 + threadIdx.x;
  if (i >= n4) return;
  float4 v = ((const float4*)src)[i];
  uint2 o;
  o.x = pack2bf(v.x, v.y);
  o.y = pack2bf(v.z, v.w);
  ((uint2*)dst)[i] = o;
}

// ---------------- W[K][N] fp32 -> Wt[N][K] bf16 (LDS-tiled) ----------------
__global__ __launch_bounds__(256) void transpose_cvt(const float* __restrict__ src,
                                                     unsigned short* __restrict__ dst,
                                                     int R, int C) {
  __shared__ float tile[32][33];
  int c0 = blockIdx.x * 32, r0 = blockIdx.y * 32;
  int tx = threadIdx.x & 31, ty = threadIdx.x >> 5;
#pragma unroll
  for (int i = 0; i < 4; ++i)
    tile[ty + i * 8][tx] = src[(r0 + ty + i * 8) * C + c0 + tx];
  __syncthreads();
#pragma unroll
  for (int i = 0; i < 4; ++i)
    dst[(c0 + ty + i * 8) * R + r0 + tx] = f2bf(tile[tx][ty + i * 8]);
}

// ---------------- GEMM: C[M][N] = A[M][K](bf16) @ Bt[N][K](bf16)^T ----------------
__global__ __launch_bounds__(256) void gemm_bt(const unsigned short* __restrict__ A,
                                               const unsigned short* __restrict__ Bt,
                                               void* __restrict__ Cout,
                                               int M, int N, int K, int outF32) {
  __shared__ __align__(16) unsigned short Als[128 * 40];
  __shared__ __align__(16) unsigned short Bls[128 * 40];
  const int tid = threadIdx.x;
  const int wave = tid >> 6, lane = tid & 63;
  const int lgrp = lane >> 4, lmod = lane & 15;
  const int wm = (wave & 1) * 64, wn = (wave >> 1) * 64;
  const int m0 = blockIdx.y * 128, n0 = blockIdx.x * 128;
  const int srow = tid >> 2;
  const int sq = (tid & 3) * 8;

  f32x4 acc[4][4] = {};

  for (int k0 = 0; k0 < K; k0 += 32) {
    __syncthreads();
#pragma unroll
    for (int it = 0; it < 2; ++it) {
      int r = srow + it * 64;
      *(u32x4*)&Als[r * 40 + sq] = *(const u32x4*)&A[(m0 + r) * K + k0 + sq];
      *(u32x4*)&Bls[r * 40 + sq] = *(const u32x4*)&Bt[(n0 + r) * K + k0 + sq];
    }
    __syncthreads();
    bf16x8 af[4], bfr[4];
#pragma unroll
    for (int mi = 0; mi < 4; ++mi)
      af[mi] = __builtin_bit_cast(bf16x8, *(const u32x4*)&Als[(wm + mi * 16 + lmod) * 40 + lgrp * 8]);
#pragma unroll
    for (int ni = 0; ni < 4; ++ni)
      bfr[ni] = __builtin_bit_cast(bf16x8, *(const u32x4*)&Bls[(wn + ni * 16 + lmod) * 40 + lgrp * 8]);
#pragma unroll
    for (int mi = 0; mi < 4; ++mi)
#pragma unroll
      for (int ni = 0; ni < 4; ++ni)
        acc[mi][ni] = __builtin_amdgcn_mfma_f32_16x16x32_bf16(af[mi], bfr[ni], acc[mi][ni], 0, 0, 0);
  }

#pragma unroll
  for (int mi = 0; mi < 4; ++mi)
#pragma unroll
    for (int ni = 0; ni < 4; ++ni)
#pragma unroll
      for (int r = 0; r < 4; ++r) {
        int row = m0 + wm + mi * 16 + lgrp * 4 + r;
        int col = n0 + wn + ni * 16 + lmod;
        float v = acc[mi][ni][r];
        if (outF32) ((float*)Cout)[row * N + col] = v;
        else ((unsigned short*)Cout)[row * N + col] = f2bf(v);
      }
}

// ---------------- RoPE + split Q/K ----------------
__global__ __launch_bounds__(256) void rope_split(const unsigned short* __restrict__ qkv,
                                                  const float* __restrict__ sinT,
                                                  const float* __restrict__ cosT,
                                                  unsigned short* __restrict__ Qh,
                                                  unsigned short* __restrict__ Kh) {
  int p = blockIdx.x * 256 + threadIdx.x;
  int s = p / 640, cp = p % 640;
  int col = cp * 2;
  unsigned int pair = *(const unsigned int*)&qkv[s * 1536 + col];
  float e = bf2f((unsigned short)(pair & 0xffff));
  float o = bf2f((unsigned short)(pair >> 16));
  if (col < 1024) {
    int h = col >> 6, d = col & 63, i = d >> 1;
    float sn = sinT[s * 32 + i], cs = cosT[s * 32 + i];
    unsigned int w = pack2bf(cs * e - sn * o, sn * e + cs * o);
    *(unsigned int*)&Qh[(h * 4096 + s) * 64 + d] = w;
  } else {
    int c = col - 1024;
    int h = c >> 6, d = c & 63, i = d >> 1;
    float sn = sinT[s * 32 + i], cs = cosT[s * 32 + i];
    unsigned int w = pack2bf(cs * e - sn * o, sn * e + cs * o);
    *(unsigned int*)&Kh[(h * 4096 + s) * 64 + d] = w;
  }
}

// ---------------- V transpose: qkv cols 1280..1535 -> Vt[4][64][4096] ----------------
__global__ __launch_bounds__(256) void transpose_v(const unsigned short* __restrict__ qkv,
                                                   unsigned short* __restrict__ Vt) {
  __shared__ unsigned short tile[32][33];
  int h = blockIdx.z;
  int d0 = blockIdx.y * 32;
  int s0 = blockIdx.x * 32;
  int tx = threadIdx.x & 31, ty = threadIdx.x >> 5;
#pragma unroll
  for (int i = 0; i < 4; ++i)
    tile[ty + i * 8][tx] = qkv[(s0 + ty + i * 8) * 1536 + 1280 + h * 64 + d0 + tx];
  __syncthreads();
#pragma unroll
  for (int i = 0; i < 4; ++i)
    Vt[(h * 64 + d0 + ty + i * 8) * 4096 + s0 + tx] = tile[tx][ty + i * 8];
}

// ---------------- Flash attention, S^T formulation (causal, start=0) ----------------
// grid (16 pairs, 16 heads), block 512 = 8 waves; each wave owns 16 q (= lmod col).
// Block processes q-block p then q-block 31-p (128 rows each) -> uniform 33 chunks.
// Key order inside each 32-key group is permuted so S^T C-layout == PV B-fragment.
__global__ __launch_bounds__(512, 2) void attn2(const unsigned short* __restrict__ Qh,
                                                const unsigned short* __restrict__ Kh,
                                                const unsigned short* __restrict__ Vt,
                                                unsigned short* __restrict__ ctx) {
  __shared__ __align__(16) unsigned short Kls[128 * 68];   // [key][d], stride 68 (b64 reads)
  __shared__ __align__(16) unsigned short Vls[64 * 136];   // [d][key], stride 136 (b128 reads)
  const int p = blockIdx.x;       // 0..15
  const int head = blockIdx.y;    // 0..15
  const int kvh = head >> 2;
  const int tid = threadIdx.x;
  const int wave = tid >> 6, lane = tid & 63;
  const int lgrp = lane >> 4, lmod = lane & 15;

  const unsigned short* Kg = Kh + (size_t)kvh * 4096 * 64;
  const unsigned short* Vg = Vt + (size_t)kvh * 64 * 4096;

  // K A-frag permuted base row: slot s=lmod -> phys row 8*(s>>2)+(s&3) (+32g+4t)
  const int kbase = (8 * (lmod >> 2) + (lmod & 3)) * 68 + lgrp * 8;
  const int vbase = lmod * 136 + lgrp * 8;

  for (int part = 0; part < 2; ++part) {
    const int qb = part ? (31 - p) : p;
    const int qrow = qb * 128 + wave * 16 + lmod;
    const unsigned short* Qg = Qh + ((size_t)head * 4096 + qrow) * 64;
    bf16x8 qf0 = __builtin_bit_cast(bf16x8, *(const u32x4*)&Qg[lgrp * 8]);
    bf16x8 qf1 = __builtin_bit_cast(bf16x8, *(const u32x4*)&Qg[32 + lgrp * 8]);
    f32x4 accO[4] = {};
    float m_i = -3e38f, l_i = 0.f;
    const int nch = qb + 1;
    for (int kc = 0; kc < nch; ++kc) {
      const int kb = kc * 128;
      __syncthreads();
      // stage K (128x64, coalesced 1KB/wave) and V^T (64x128)
#pragma unroll
      for (int i = 0; i < 2; ++i) {
        int ii = tid + i * 512;
        int r = ii >> 3, sg = (ii & 7) * 8;
        u32x4 dK = *(const u32x4*)&Kg[(size_t)(kb + r) * 64 + sg];
        uint2* pd = (uint2*)&Kls[r * 68 + sg];
        pd[0] = make_uint2(dK[0], dK[1]);
        pd[1] = make_uint2(dK[2], dK[3]);
      }
#pragma unroll
      for (int i = 0; i < 2; ++i) {
        int ii = tid + i * 512;
        int r = ii >> 4, sg = (ii & 15) * 8;
        *(u32x4*)&Vls[r * 136 + sg] = *(const u32x4*)&Vg[(size_t)r * 4096 + kb + sg];
      }
      __syncthreads();

      // S^T = K @ Q^T : 8 tiles (4 key-groups x 2), A=K(perm rows), B=Q
      f32x4 s[4][2];
#pragma unroll
      for (int g = 0; g < 4; ++g)
#pragma unroll
        for (int t = 0; t < 2; ++t) {
          const unsigned short* ka = &Kls[kbase + (32 * g + 4 * t) * 68];
          uint2 a0 = *(const uint2*)&ka[0];
          uint2 a1 = *(const uint2*)&ka[4];
          uint2 b0 = *(const uint2*)&ka[32];
          uint2 b1 = *(const uint2*)&ka[36];
          u32x4 lo = {a0.x, a0.y, a1.x, a1.y};
          u32x4 hi = {b0.x, b0.y, b1.x, b1.y};
          f32x4 z = {};
          z = __builtin_amdgcn_mfma_f32_16x16x32_bf16(__builtin_bit_cast(bf16x8, lo), qf0, z, 0, 0, 0);
          z = __builtin_amdgcn_mfma_f32_16x16x32_bf16(__builtin_bit_cast(bf16x8, hi), qf1, z, 0, 0, 0);
          s[g][t] = z;
        }

      // causal mask (wave-uniform skip for interior chunks)
      if (kb + 127 > qb * 128 + wave * 16) {
#pragma unroll
        for (int g = 0; g < 4; ++g)
#pragma unroll
          for (int t = 0; t < 2; ++t)
#pragma unroll
            for (int r = 0; r < 4; ++r) {
              int key = kb + 32 * g + 8 * lgrp + 4 * t + r;
              if (key > qrow) s[g][t][r] = -3e38f;
            }
      }

      // online softmax: in-register tree + 2 shfl (all 32 keys of a lane share q=lmod)
      f32x4 v0 = s[0][0], v1 = s[0][1];
#pragma unroll
      for (int g = 1; g < 4; ++g) {
#pragma unroll
        for (int r = 0; r < 4; ++r) {
          v0[r] = fmaxf(v0[r], s[g][0][r]);
          v1[r] = fmaxf(v1[r], s[g][1][r]);
        }
      }
      float mx = fmaxf(fmaxf(fmaxf(v0[0], v0[1]), fmaxf(v0[2], v0[3])),
                       fmaxf(fmaxf(v1[0], v1[1]), fmaxf(v1[2], v1[3])));
      mx = fmaxf(mx, __shfl_xor(mx, 16, 64));
      mx = fmaxf(mx, __shfl_xor(mx, 32, 64));
      float mnew = fmaxf(m_i, mx);
      float alpha = __expf((m_i - mnew) * 0.125f);
      m_i = mnew;
      const float bia = mnew * 0.125f;
      f32x4 e[4][2];
      f32x4 su = {};
#pragma unroll
      for (int g = 0; g < 4; ++g)
#pragma unroll
        for (int t = 0; t < 2; ++t)
#pragma unroll
          for (int r = 0; r < 4; ++r) {
            float ev = __expf(s[g][t][r] * 0.125f - bia);
            e[g][t][r] = ev;
            su[r] += ev;
          }
      float rs = (su[0] + su[1]) + (su[2] + su[3]);
      rs += __shfl_xor(rs, 16, 64);
      rs += __shfl_xor(rs, 32, 64);
      l_i = l_i * alpha + rs;
#pragma unroll
      for (int dt = 0; dt < 4; ++dt)
#pragma unroll
        for (int r = 0; r < 4; ++r) accO[dt][r] *= alpha;

      // O^T += V^T @ P^T : P B-frag comes straight from e[] registers
#pragma unroll
      for (int g = 0; g < 4; ++g) {
        u32x4 pk;
        pk[0] = pack2bf(e[g][0][0], e[g][0][1]);
        pk[1] = pack2bf(e[g][0][2], e[g][0][3]);
        pk[2] = pack2bf(e[g][1][0], e[g][1][1]);
        pk[3] = pack2bf(e[g][1][2], e[g][1][3]);
        bf16x8 pf = __builtin_bit_cast(bf16x8, pk);
#pragma unroll
        for (int dt = 0; dt < 4; ++dt) {
          bf16x8 vf = __builtin_bit_cast(bf16x8, *(const u32x4*)&Vls[vbase + dt * 2176 + 32 * g]);
          accO[dt] = __builtin_amdgcn_mfma_f32_16x16x32_bf16(vf, pf, accO[dt], 0, 0, 0);
        }
      }
    }

    float inv = 1.f / l_i;
#pragma unroll
    for (int dt = 0; dt < 4; ++dt) {
      uint2 o;
      o.x = pack2bf(accO[dt][0] * inv, accO[dt][1] * inv);
      o.y = pack2bf(accO[dt][2] * inv, accO[dt][3] * inv);
      *(uint2*)&ctx[(size_t)qrow * 1024 + head * 64 + dt * 16 + lgrp * 4] = o;
    }
  }
}

extern "C" void kernel_launch(void* const* d_in, const int* in_sizes, int n_in,
                              void* d_out, int out_size, void* d_ws, size_t ws_size,
                              hipStream_t stream) {
  const float* x    = (const float*)d_in[0];
  const float* wq   = (const float*)d_in[3];
  const float* wk   = (const float*)d_in[4];
  const float* wv   = (const float*)d_in[5];
  const float* wo   = (const float*)d_in[6];
  const float* sinT = (const float*)d_in[7];
  const float* cosT = (const float*)d_in[8];

  unsigned short* ws    = (unsigned short*)d_ws;
  unsigned short* xb    = ws;                          // 4096*1024
  unsigned short* wtqkv = xb + 4096 * 1024;            // 1536*1024
  unsigned short* wot   = wtqkv + 1536 * 1024;         // 1024*1024
  unsigned short* qkv   = wot + 1024 * 1024;           // 4096*1536
  unsigned short* Qh    = qkv + 4096 * 1536;           // 16*4096*64
  unsigned short* Kh    = Qh + 16 * 4096 * 64;         // 4*4096*64
  unsigned short* Vt    = Kh + 4 * 4096 * 64;          // 4*64*4096
  unsigned short* ctx   = Vt + 4 * 64 * 4096;          // 4096*1024
  float* out = (float*)d_out;

  cvt_f32_bf16<<<4096, 256, 0, stream>>>(x, xb, 4096 * 1024 / 4);
  transpose_cvt<<<dim3(32, 32), 256, 0, stream>>>(wq, wtqkv, 1024, 1024);
  transpose_cvt<<<dim3(8, 32), 256, 0, stream>>>(wk, wtqkv + 1024 * 1024, 1024, 256);
  transpose_cvt<<<dim3(8, 32), 256, 0, stream>>>(wv, wtqkv + 1280 * 1024, 1024, 256);
  transpose_cvt<<<dim3(32, 32), 256, 0, stream>>>(wo, wot, 1024, 1024);

  gemm_bt<<<dim3(12, 32), 256, 0, stream>>>(xb, wtqkv, qkv, 4096, 1536, 1024, 0);

  rope_split<<<10240, 256, 0, stream>>>(qkv, sinT, cosT, Qh, Kh);
  transpose_v<<<dim3(128, 2, 4), 256, 0, stream>>>(qkv, Vt);

  attn2<<<dim3(16, 16), 512, 0, stream>>>(Qh, Kh, Vt, ctx);

  gemm_bt<<<dim3(8, 32), 256, 0, stream>>>(ctx, wot, out, 4096, 1024, 1024, 1);
}

// Round 3
// 269.467 us; speedup vs baseline: 1.5822x; 1.1441x over previous
//
#include <hip/hip_runtime.h>

typedef __bf16 bf16x8 __attribute__((ext_vector_type(8)));
typedef float f32x4 __attribute__((ext_vector_type(4)));
typedef unsigned int u32x4 __attribute__((ext_vector_type(4)));

typedef const void __attribute__((address_space(1)))* gas1;
typedef void __attribute__((address_space(3)))* las3;

__device__ __forceinline__ unsigned short f2bf(float f) {
  unsigned int u = __builtin_bit_cast(unsigned int, f);
  u += 0x7fffu + ((u >> 16) & 1u);   // RNE
  return (unsigned short)(u >> 16);
}
__device__ __forceinline__ float bf2f(unsigned short h) {
  unsigned int u = ((unsigned int)h) << 16;
  return __builtin_bit_cast(float, u);
}
__device__ __forceinline__ unsigned int pack2bf(float lo, float hi) {
  return (unsigned int)f2bf(lo) | ((unsigned int)f2bf(hi) << 16);
}
// truncating pack (P values in [0,1]; bias ~2^-9 rel, fine vs threshold)
__device__ __forceinline__ unsigned int packtr(float lo, float hi) {
  return __builtin_amdgcn_perm(__builtin_bit_cast(unsigned int, hi),
                               __builtin_bit_cast(unsigned int, lo), 0x07060302u);
}

// ---------------- x -> bf16 ----------------
__global__ __launch_bounds__(256) void cvt_f32_bf16(const float* __restrict__ src,
                                                    unsigned short* __restrict__ dst, int n4) {
  int i = blockIdx.x * 256 + threadIdx.x;
  if (i >= n4) return;
  float4 v = ((const float4*)src)[i];
  uint2 o;
  o.x = pack2bf(v.x, v.y);
  o.y = pack2bf(v.z, v.w);
  ((uint2*)dst)[i] = o;
}

// ---------------- W[K][N] fp32 -> Wt[N][K] bf16 (LDS-tiled) ----------------
__global__ __launch_bounds__(256) void transpose_cvt(const float* __restrict__ src,
                                                     unsigned short* __restrict__ dst,
                                                     int R, int C) {
  __shared__ float tile[32][33];
  int c0 = blockIdx.x * 32, r0 = blockIdx.y * 32;
  int tx = threadIdx.x & 31, ty = threadIdx.x >> 5;
#pragma unroll
  for (int i = 0; i < 4; ++i)
    tile[ty + i * 8][tx] = src[(r0 + ty + i * 8) * C + c0 + tx];
  __syncthreads();
#pragma unroll
  for (int i = 0; i < 4; ++i)
    dst[(c0 + ty + i * 8) * R + r0 + tx] = f2bf(tile[tx][ty + i * 8]);
}

// ---------------- GEMM (m97-style): C[M][N] = A[M][K] @ Bt[N][K]^T, bf16 ----------------
// 128x128 tile, 256 thr (4 waves 2x2), BK=32, global_load_lds width 16, stride-32 LDS.
__global__ __launch_bounds__(256, 2) void gemm_bt2(const unsigned short* __restrict__ A,
                                                   const unsigned short* __restrict__ Bt,
                                                   void* __restrict__ Cout,
                                                   int M, int N, int K, int outF32) {
  __shared__ __align__(16) unsigned short Als[128 * 32];
  __shared__ __align__(16) unsigned short Bls[128 * 32];
  const int tid = threadIdx.x;
  const int wave = tid >> 6, lane = tid & 63;
  const int lgrp = lane >> 4, lmod = lane & 15;
  const int wm = (wave & 1) * 64, wn = (wave >> 1) * 64;
  const int m0 = blockIdx.y * 128, n0 = blockIdx.x * 128;

  f32x4 acc[4][4] = {};

  for (int k0 = 0; k0 < K; k0 += 32) {
    __syncthreads();
#pragma unroll
    for (int it = 0; it < 2; ++it) {
      int idx = tid + it * 256;
      int rr = idx >> 2, cc = (idx & 3) * 8;
      __builtin_amdgcn_global_load_lds((gas1)(const void*)&A[(size_t)(m0 + rr) * K + k0 + cc],
                                       (las3)(void*)&Als[(it * 256 + wave * 64) * 8], 16, 0, 0);
      __builtin_amdgcn_global_load_lds((gas1)(const void*)&Bt[(size_t)(n0 + rr) * K + k0 + cc],
                                       (las3)(void*)&Bls[(it * 256 + wave * 64) * 8], 16, 0, 0);
    }
    __syncthreads();
    bf16x8 af[4], bfr[4];
#pragma unroll
    for (int mi = 0; mi < 4; ++mi)
      af[mi] = __builtin_bit_cast(bf16x8, *(const u32x4*)&Als[(wm + mi * 16 + lmod) * 32 + lgrp * 8]);
#pragma unroll
    for (int ni = 0; ni < 4; ++ni)
      bfr[ni] = __builtin_bit_cast(bf16x8, *(const u32x4*)&Bls[(wn + ni * 16 + lmod) * 32 + lgrp * 8]);
#pragma unroll
    for (int mi = 0; mi < 4; ++mi)
#pragma unroll
      for (int ni = 0; ni < 4; ++ni)
        acc[mi][ni] = __builtin_amdgcn_mfma_f32_16x16x32_bf16(af[mi], bfr[ni], acc[mi][ni], 0, 0, 0);
  }

#pragma unroll
  for (int mi = 0; mi < 4; ++mi)
#pragma unroll
    for (int ni = 0; ni < 4; ++ni)
#pragma unroll
      for (int r = 0; r < 4; ++r) {
        int row = m0 + wm + mi * 16 + lgrp * 4 + r;
        int col = n0 + wn + ni * 16 + lmod;
        float v = acc[mi][ni][r];
        if (outF32) ((float*)Cout)[row * N + col] = v;
        else ((unsigned short*)Cout)[row * N + col] = f2bf(v);
      }
}

// ---------------- RoPE + split Q/K (Q pre-scaled by 0.125/ln2 for exp2 softmax) --------
__global__ __launch_bounds__(256) void rope_split(const unsigned short* __restrict__ qkv,
                                                  const float* __restrict__ sinT,
                                                  const float* __restrict__ cosT,
                                                  unsigned short* __restrict__ Qh,
                                                  unsigned short* __restrict__ Kh) {
  const float qscale = 0.18033688011112042f;   // 0.125 * log2(e)
  int p = blockIdx.x * 256 + threadIdx.x;
  int s = p / 640, cp = p % 640;
  int col = cp * 2;
  unsigned int pair = *(const unsigned int*)&qkv[s * 1536 + col];
  float e = bf2f((unsigned short)(pair & 0xffff));
  float o = bf2f((unsigned short)(pair >> 16));
  if (col < 1024) {
    int h = col >> 6, d = col & 63, i = d >> 1;
    float sn = sinT[s * 32 + i], cs = cosT[s * 32 + i];
    unsigned int w = pack2bf((cs * e - sn * o) * qscale, (sn * e + cs * o) * qscale);
    *(unsigned int*)&Qh[(h * 4096 + s) * 64 + d] = w;
  } else {
    int c = col - 1024;
    int h = c >> 6, d = c & 63, i = d >> 1;
    float sn = sinT[s * 32 + i], cs = cosT[s * 32 + i];
    unsigned int w = pack2bf(cs * e - sn * o, sn * e + cs * o);
    *(unsigned int*)&Kh[(h * 4096 + s) * 64 + d] = w;
  }
}

// ---------------- V transpose: qkv cols 1280..1535 -> Vt[4][64][4096] ----------------
__global__ __launch_bounds__(256) void transpose_v(const unsigned short* __restrict__ qkv,
                                                   unsigned short* __restrict__ Vt) {
  __shared__ unsigned short tile[32][33];
  int h = blockIdx.z;
  int d0 = blockIdx.y * 32;
  int s0 = blockIdx.x * 32;
  int tx = threadIdx.x & 31, ty = threadIdx.x >> 5;
#pragma unroll
  for (int i = 0; i < 4; ++i)
    tile[ty + i * 8][tx] = qkv[(s0 + ty + i * 8) * 1536 + 1280 + h * 64 + d0 + tx];
  __syncthreads();
#pragma unroll
  for (int i = 0; i < 4; ++i)
    Vt[(h * 64 + d0 + ty + i * 8) * 4096 + s0 + tx] = tile[tx][ty + i * 8];
}

// ---------------- Flash attention, S^T formulation, q=32/wave ----------------
// grid 512: blockIdx.x = qidx*16+head; qb = qidx<16 ? 31-qidx : qidx-16 (heavy first,
// complementary pairs per CU). Block = 4 waves x 32 q = 128 q-rows; chunks of 128 keys.
// Key order permuted per 32-key group so S^T C-layout == PV B-fragment (verified R1).
__global__ __launch_bounds__(256, 2) void attn3(const unsigned short* __restrict__ Qh,
                                                const unsigned short* __restrict__ Kh,
                                                const unsigned short* __restrict__ Vt,
                                                unsigned short* __restrict__ ctx) {
  __shared__ __align__(16) unsigned short Kls[128 * 68];   // [key][d], stride 68
  __shared__ __align__(16) unsigned short Vls[64 * 136];   // [d][key], stride 136
  const int bx = blockIdx.x;
  const int head = bx & 15;
  const int qidx = bx >> 4;
  const int qb = (qidx < 16) ? (31 - qidx) : (qidx - 16);
  const int kvh = head >> 2;
  const int tid = threadIdx.x;
  const int wave = tid >> 6, lane = tid & 63;
  const int lgrp = lane >> 4, lmod = lane & 15;
  const int qbase = qb * 128;

  const unsigned short* Kg = Kh + (size_t)kvh * 4096 * 64;
  const unsigned short* Vg = Vt + (size_t)kvh * 64 * 4096;

  // Q fragments: 2 q-tiles of 16 per wave
  bf16x8 qf[2][2];
  int qrow[2];
#pragma unroll
  for (int qt = 0; qt < 2; ++qt) {
    qrow[qt] = qbase + wave * 32 + qt * 16 + lmod;
    const unsigned short* Qg = Qh + ((size_t)head * 4096 + qrow[qt]) * 64;
    qf[qt][0] = __builtin_bit_cast(bf16x8, *(const u32x4*)&Qg[lgrp * 8]);
    qf[qt][1] = __builtin_bit_cast(bf16x8, *(const u32x4*)&Qg[32 + lgrp * 8]);
  }

  const int kbase = (8 * (lmod >> 2) + (lmod & 3)) * 68 + lgrp * 8;
  const int vbase = lmod * 136 + lgrp * 8;

  f32x4 accO[2][4] = {};
  float m_i[2] = {-3e38f, -3e38f}, l_i[2] = {0.f, 0.f};

  for (int kc = 0; kc <= qb; ++kc) {
    const int kb = kc * 128;
    __syncthreads();
#pragma unroll
    for (int i = 0; i < 4; ++i) {
      int ii = tid + i * 256;
      int r = ii >> 3, sg = (ii & 7) * 8;
      u32x4 dK = *(const u32x4*)&Kg[(size_t)(kb + r) * 64 + sg];
      uint2* pd = (uint2*)&Kls[r * 68 + sg];
      pd[0] = make_uint2(dK[0], dK[1]);
      pd[1] = make_uint2(dK[2], dK[3]);
    }
#pragma unroll
    for (int i = 0; i < 4; ++i) {
      int ii = tid + i * 256;
      int r = ii >> 4, sg = (ii & 15) * 8;
      *(u32x4*)&Vls[r * 136 + sg] = *(const u32x4*)&Vg[(size_t)r * 4096 + kb + sg];
    }
    __syncthreads();

    // S^T = K @ Q^T : A-frags shared across both q-tiles
    f32x4 s[4][2][2];
#pragma unroll
    for (int g = 0; g < 4; ++g)
#pragma unroll
      for (int t = 0; t < 2; ++t) {
        const unsigned short* ka = &Kls[kbase + (32 * g + 4 * t) * 68];
        uint2 a0 = *(const uint2*)&ka[0];
        uint2 a1 = *(const uint2*)&ka[4];
        uint2 b0 = *(const uint2*)&ka[32];
        uint2 b1 = *(const uint2*)&ka[36];
        u32x4 lo = {a0.x, a0.y, a1.x, a1.y};
        u32x4 hi = {b0.x, b0.y, b1.x, b1.y};
        bf16x8 alo = __builtin_bit_cast(bf16x8, lo);
        bf16x8 ahi = __builtin_bit_cast(bf16x8, hi);
#pragma unroll
        for (int qt = 0; qt < 2; ++qt) {
          f32x4 z = {};
          z = __builtin_amdgcn_mfma_f32_16x16x32_bf16(alo, qf[qt][0], z, 0, 0, 0);
          z = __builtin_amdgcn_mfma_f32_16x16x32_bf16(ahi, qf[qt][1], z, 0, 0, 0);
          s[g][t][qt] = z;
        }
      }

    // causal mask (wave-uniform skip when chunk fully below q-tile)
#pragma unroll
    for (int qt = 0; qt < 2; ++qt) {
      if (kb + 127 > qbase + wave * 32 + qt * 16) {
#pragma unroll
        for (int g = 0; g < 4; ++g)
#pragma unroll
          for (int t = 0; t < 2; ++t)
#pragma unroll
            for (int r = 0; r < 4; ++r) {
              int key = kb + 32 * g + 8 * lgrp + 4 * t + r;
              if (key > qrow[qt]) s[g][t][qt][r] = -3e38f;
            }
      }
    }

    // online softmax per q-tile (scores already in log2 units)
#pragma unroll
    for (int qt = 0; qt < 2; ++qt) {
      f32x4 v0 = s[0][0][qt], v1 = s[0][1][qt];
#pragma unroll
      for (int g = 1; g < 4; ++g)
#pragma unroll
        for (int r = 0; r < 4; ++r) {
          v0[r] = fmaxf(v0[r], s[g][0][qt][r]);
          v1[r] = fmaxf(v1[r], s[g][1][qt][r]);
        }
      float mx = fmaxf(fmaxf(fmaxf(v0[0], v0[1]), fmaxf(v0[2], v0[3])),
                       fmaxf(fmaxf(v1[0], v1[1]), fmaxf(v1[2], v1[3])));
      mx = fmaxf(mx, __shfl_xor(mx, 16, 64));
      mx = fmaxf(mx, __shfl_xor(mx, 32, 64));
      float mnew = fmaxf(m_i[qt], mx);
      float alpha = __builtin_amdgcn_exp2f(m_i[qt] - mnew);
      m_i[qt] = mnew;
      f32x4 su = {};
#pragma unroll
      for (int g = 0; g < 4; ++g)
#pragma unroll
        for (int t = 0; t < 2; ++t)
#pragma unroll
          for (int r = 0; r < 4; ++r) {
            float ev = __builtin_amdgcn_exp2f(s[g][t][qt][r] - mnew);
            s[g][t][qt][r] = ev;
            su[r] += ev;
          }
      float rs = (su[0] + su[1]) + (su[2] + su[3]);
      rs += __shfl_xor(rs, 16, 64);
      rs += __shfl_xor(rs, 32, 64);
      l_i[qt] = l_i[qt] * alpha + rs;
#pragma unroll
      for (int dt = 0; dt < 4; ++dt)
#pragma unroll
        for (int r = 0; r < 4; ++r) accO[qt][dt][r] *= alpha;
    }

    // O^T += V^T @ P^T : V A-frags shared across both q-tiles
#pragma unroll
    for (int g = 0; g < 4; ++g) {
      bf16x8 pf[2];
#pragma unroll
      for (int qt = 0; qt < 2; ++qt) {
        u32x4 pk;
        pk[0] = packtr(s[g][0][qt][0], s[g][0][qt][1]);
        pk[1] = packtr(s[g][0][qt][2], s[g][0][qt][3]);
        pk[2] = packtr(s[g][1][qt][0], s[g][1][qt][1]);
        pk[3] = packtr(s[g][1][qt][2], s[g][1][qt][3]);
        pf[qt] = __builtin_bit_cast(bf16x8, pk);
      }
#pragma unroll
      for (int dt = 0; dt < 4; ++dt) {
        bf16x8 vf = __builtin_bit_cast(bf16x8, *(const u32x4*)&Vls[vbase + dt * 2176 + 32 * g]);
        accO[0][dt] = __builtin_amdgcn_mfma_f32_16x16x32_bf16(vf, pf[0], accO[0][dt], 0, 0, 0);
        accO[1][dt] = __builtin_amdgcn_mfma_f32_16x16x32_bf16(vf, pf[1], accO[1][dt], 0, 0, 0);
      }
    }
  }

#pragma unroll
  for (int qt = 0; qt < 2; ++qt) {
    float inv = 1.f / l_i[qt];
#pragma unroll
    for (int dt = 0; dt < 4; ++dt) {
      uint2 o;
      o.x = pack2bf(accO[qt][dt][0] * inv, accO[qt][dt][1] * inv);
      o.y = pack2bf(accO[qt][dt][2] * inv, accO[qt][dt][3] * inv);
      *(uint2*)&ctx[(size_t)qrow[qt] * 1024 + head * 64 + dt * 16 + lgrp * 4] = o;
    }
  }
}

extern "C" void kernel_launch(void* const* d_in, const int* in_sizes, int n_in,
                              void* d_out, int out_size, void* d_ws, size_t ws_size,
                              hipStream_t stream) {
  const float* x    = (const float*)d_in[0];
  const float* wq   = (const float*)d_in[3];
  const float* wk   = (const float*)d_in[4];
  const float* wv   = (const float*)d_in[5];
  const float* wo   = (const float*)d_in[6];
  const float* sinT = (const float*)d_in[7];
  const float* cosT = (const float*)d_in[8];

  unsigned short* ws    = (unsigned short*)d_ws;
  unsigned short* xb    = ws;                          // 4096*1024
  unsigned short* wtqkv = xb + 4096 * 1024;            // 1536*1024
  unsigned short* wot   = wtqkv + 1536 * 1024;         // 1024*1024
  unsigned short* qkv   = wot + 1024 * 1024;           // 4096*1536
  unsigned short* Qh    = qkv + 4096 * 1536;           // 16*4096*64
  unsigned short* Kh    = Qh + 16 * 4096 * 64;         // 4*4096*64
  unsigned short* Vt    = Kh + 4 * 4096 * 64;          // 4*64*4096
  unsigned short* ctx   = Vt + 4 * 64 * 4096;          // 4096*1024
  float* out = (float*)d_out;

  cvt_f32_bf16<<<4096, 256, 0, stream>>>(x, xb, 4096 * 1024 / 4);
  transpose_cvt<<<dim3(32, 32), 256, 0, stream>>>(wq, wtqkv, 1024, 1024);
  transpose_cvt<<<dim3(8, 32), 256, 0, stream>>>(wk, wtqkv + 1024 * 1024, 1024, 256);
  transpose_cvt<<<dim3(8, 32), 256, 0, stream>>>(wv, wtqkv + 1280 * 1024, 1024, 256);
  transpose_cvt<<<dim3(32, 32), 256, 0, stream>>>(wo, wot, 1024, 1024);

  gemm_bt2<<<dim3(12, 32), 256, 0, stream>>>(xb, wtqkv, qkv, 4096, 1536, 1024, 0);

  rope_split<<<10240, 256, 0, stream>>>(qkv, sinT, cosT, Qh, Kh);
  transpose_v<<<dim3(128, 2, 4), 256, 0, stream>>>(qkv, Vt);

  attn3<<<dim3(512), 256, 0, stream>>>(Qh, Kh, Vt, ctx);

  gemm_bt2<<<dim3(8, 32), 256, 0, stream>>>(ctx, wot, out, 4096, 1024, 1024, 1);
}